// Round 10
// baseline (319.879 us; speedup 1.0000x reference)
//
#include <hip/hip_runtime.h>

typedef _Float16 f16x8 __attribute__((ext_vector_type(8)));
typedef float    f32x4 __attribute__((ext_vector_type(4)));

constexpr int BATCH = 2048;
constexpr int SEQ   = 512;
constexpr int H     = 50;
constexpr int NB    = 8;     // batch per block -> 256 blocks = 1 per CU
constexpr int NT    = 832;   // 13 waves, ALL MFMA-active
constexpr int KQ    = 4;     // panel k-chunks of 32 (K=128)
constexpr int PSZ   = 1024;  // compact panel halfs per buffer (2 KB)

__device__ __forceinline__ float fexp2(float x) { return __builtin_amdgcn_exp2f(x); }
__device__ __forceinline__ float frcp(float x)  { return __builtin_amdgcn_rcpf(x); }
__device__ __forceinline__ _Float16 f16hi(float w) { return (_Float16)w; }
__device__ __forceinline__ _Float16 f16lo(float w) {
    _Float16 h = (_Float16)w; return (_Float16)(w - (float)h);
}
// compact B-panel address (halfs) for value (k, c), k<128, c<8 (single copy)
__device__ __forceinline__ int caddr(int k, int c) {
    return ((k >> 3) * 64) + c * 8 + (k & 7);
}
union H2U { unsigned u; _Float16 h[2]; };

constexpr float K1 = 1.4426950408889634f;   // log2(e)
constexpr float K2 = 2.8853900817779268f;   // 2*log2(e)

// === r17: r16 frame + combined multi-phase micro-cuts ===
// Model (r9-r16 ledger): step = convoyed co-critical phases (LDS service ~
// 350-450cy/CU, MFMA ~100-300, act issue ~400-500cy/SIMD with 8 quarter-rate
// trans/chain, barrier+latency ~200) -> single-lever cuts move time only by
// their phase share (r15: VALU-5/chain -> -2us; r16: LDS bytes -50% -> -6us).
// So cut several phases at once, keeping the proven frame:
//  (1) x returns to panel rows 50,51 (zero-pad rows of chunk 1; r9-proven
//      hi/lo f16 scheme, prescaled): A[50]=hi(rsc*Wih0), A[51]=lo(rsc*Wih0);
//      B rows = x_hi,x_lo staged by 8 act-idle lanes of wave 12 (jj>=50).
//      Removes 4 fma + 1 ds_read_b32 per wave-step (and 13 reads/CU-step).
//  (2) rcp-merge: c = (c*P + sgn*(1-Eg)*F) * rcp(P*F), P=(1+Ei)(1+Eg),
//      F=1+Ef -> one rcp for the c-update (trans 8 -> 7 per chain).
// Everything else byte-identical to r16: compact single-copy broadcast
// panel (lanes nn and nn+8 share addresses), prescaled gates (-K1/-K2
// folded into A/bias at setup), three 2-deep MFMA chains, 1 barrier/step.
// k-map: k[0,50)=h1 | k=50,51: x_hi,x_lo | k[52,64)=0 | k[64,114)=h2 | 0.
// Schedule: step s reads sB[s&1] = {h1(s-1), x(s), h2(s-2)}, writes
// sB[(s+1)&1] = {h1(s), x(s+1), h2(s-1)}; edges s=0,511,512 peeled.

__global__ __launch_bounds__(NT, 3) void lstm2_r17(
    const float* __restrict__ x,
    const float* __restrict__ Wih0, const float* __restrict__ Whh0,
    const float* __restrict__ bih0, const float* __restrict__ bhh0,
    const float* __restrict__ Wih1, const float* __restrict__ Whh1,
    const float* __restrict__ bih1, const float* __restrict__ bhh1,
    const float* __restrict__ fcW,  const float* __restrict__ fcb,
    float* __restrict__ out)
{
    __shared__ _Float16 sB[2][PSZ];     // double-buffered compact panel, 4 KB
    __shared__ unsigned sXu[SEQ * NB];  // pre-split x (hi,lo) pairs, 16 KB
    __shared__ float    sH2f[H * NB];   // final h2

    const int t    = threadIdx.x;
    const int wave = t >> 6, lane = t & 63;
    const int quad = lane >> 4, nn = lane & 15;
    const int bbase = blockIdx.x * NB;

    // zero both panels (rows k in [52,64) and [114,128) must stay 0 forever)
    for (int i = t; i < 2 * PSZ; i += NT) ((_Float16*)sB)[i] = (_Float16)0.f;

    // ---- pre-stage ALL x as packed f16 hi/lo pairs (coalesced along s) ----
    for (int i = t; i < NB * SEQ; i += NT) {
        const int b = i >> 9, s = i & (SEQ - 1);
        const float xv = x[(bbase + b) * SEQ + s];
        H2U p; p.h[0] = f16hi(xv); p.h[1] = f16lo(xv);
        sXu[s * NB + b] = p.u;
    }

    // ---- constant A-fragments (PRESCALED); wave w owns tile m = w ----
    const int  m    = wave;
    const int  jr   = m * 4 + (nn >> 2);     // hidden unit of A phys row nn
    const int  gate = nn & 3;                // gate of A phys row nn
    const bool rv   = (jr < H);
    const int  lrow = gate * H + jr;         // logical W row
    const float rsc = (gate == 2) ? -K2 : -K1;   // row prescale

    f16x8 a0[2];       // L0: -s*Whh0 (k<50) + x weights hi/lo (k=50,51)
    f16x8 a1[KQ];      // L1: -s*Wih1 (k<50) + -s*Whh1 (k in [64,114))
    #pragma unroll
    for (int q = 0; q < 2; ++q) {
        #pragma unroll
        for (int j = 0; j < 8; ++j) {
            const int k = q * 32 + quad * 8 + j;
            _Float16 v = (_Float16)0.f;
            if (rv) {
                if      (k < 50)   v = (_Float16)(rsc * Whh0[lrow * H + k]);
                else if (k == 50)  v = f16hi(rsc * Wih0[lrow]);
                else if (k == 51)  v = f16lo(rsc * Wih0[lrow]);
            }
            a0[q][j] = v;
        }
    }
    #pragma unroll
    for (int q = 0; q < KQ; ++q) {
        #pragma unroll
        for (int j = 0; j < 8; ++j) {
            const int k = q * 32 + quad * 8 + j;
            _Float16 v = (_Float16)0.f;
            if (rv) {
                if      (k < 50)              v = (_Float16)(rsc * Wih1[lrow * H + k]);
                else if (k >= 64 && k < 114)  v = (_Float16)(rsc * Whh1[lrow * H + (k - 64)]);
            }
            a1[q][j] = v;
        }
    }

    // per-lane combine identity
    const int  hiH  = nn >> 3;               // 0: L0 act, 1: L1 act
    const int  col  = nn & 7;                // batch
    const int  jj   = m * 4 + quad;          // hidden unit (valid < 50)
    const bool jv   = (jj < H);

    f32x4 b0v = {0,0,0,0}, b1v = {0,0,0,0};
    if (jv) {
        #pragma unroll
        for (int r = 0; r < 4; ++r) {
            const float s = (r == 2) ? -K2 : -K1;   // reg r = gate r
            b0v[r] = s * (bih0[r * H + jj] + bhh0[r * H + jj]);
            b1v[r] = s * (bih1[r * H + jj] + bhh1[r * H + jj]);
        }
    }

    // read bases: lanes nn and nn+8 share the address -> free broadcast
    const int rb0 = 0 * 256 + quad * 64 + col * 8;
    const int rb1 = 1 * 256 + quad * 64 + col * 8;
    const int rb2 = 2 * 256 + quad * 64 + col * 8;
    const int rb3 = 3 * 256 + quad * 64 + col * 8;
    // single write slot: k = hiH*64 + jj
    const int  wH   = caddr(hiH * 64 + jj, col);
    const bool wrOK = jv;
    float c = 0.f;                           // c0 (lo lanes) or c1 (hi lanes)

    // x-staging: 8 act-idle lanes of wave 12 (quad 2, lo half) write x(s+1)
    // rows 50,51 (adjacent halfs -> one u32) into the write panel.
    const bool xstage = (wave == 12) && (quad == 2) && (hiH == 0);
    const int  xwr    = (384 + col * 8 + 2) >> 1;   // u32 index into panel

    __syncthreads();
    if (t < NB)                              // x(0) into panel 0
        ((unsigned*)sB[0])[(384 + t * 8 + 2) >> 1] = sXu[t];
    __syncthreads();

    auto body = [&](int s, const _Float16* __restrict__ br,
                    _Float16* __restrict__ bw,
                    bool doL0, bool doL1, bool last) {
        const f16x8 bq0 = *(const f16x8*)&br[rb0];
        const f16x8 bq1 = *(const f16x8*)&br[rb1];
        const f16x8 bq2 = *(const f16x8*)&br[rb2];
        const f16x8 bq3 = *(const f16x8*)&br[rb3];

        // three independent 2-deep chains (x rides in chunk 1 of the L0 chain)
        f32x4 g0 = b0v;
        g0 = __builtin_amdgcn_mfma_f32_16x16x32_f16(a0[0], bq0, g0, 0, 0, 0);
        g0 = __builtin_amdgcn_mfma_f32_16x16x32_f16(a0[1], bq1, g0, 0, 0, 0);
        f32x4 g1a = b1v;
        g1a = __builtin_amdgcn_mfma_f32_16x16x32_f16(a1[0], bq0, g1a, 0, 0, 0);
        g1a = __builtin_amdgcn_mfma_f32_16x16x32_f16(a1[1], bq1, g1a, 0, 0, 0);
        f32x4 g1b = {0, 0, 0, 0};
        g1b = __builtin_amdgcn_mfma_f32_16x16x32_f16(a1[2], bq2, g1b, 0, 0, 0);
        g1b = __builtin_amdgcn_mfma_f32_16x16x32_f16(a1[3], bq3, g1b, 0, 0, 0);

        float g[4];
        #pragma unroll
        for (int r = 0; r < 4; ++r)
            g[r] = hiH ? (g1a[r] + g1b[r]) : g0[r];

        // g[0]=-i, g[1]=-f, g[3]=-o (log2-folded); g[2]=-2*g~ (log2)
        const bool act = hiH ? doL1 : doL0;
        if (act) {
            float Ei = fexp2(g[0]);                  // e^{-i}
            float Ef = fexp2(g[1]);                  // e^{-f}
            float Eg = fexp2(-fabsf(g[2]));          // e^{-2|g~|}
            float Eo = fexp2(g[3]);                  // e^{-o}
            float P  = (1.f + Ei) * (1.f + Eg);
            float F  = 1.f + Ef;
            float R  = frcp(P * F);                  // merged: 1 rcp for c-update
            float tn = copysignf((1.f - Eg) * F, -g[2]);
            c = fmaf(c, P, tn) * R;                  // c/F + tanh*sig(i)
            float Ec = fexp2(-fabsf(K2 * c));        // e^{-2|c|}
            float h  = copysignf((1.f - Ec) * frcp((1.f + Eo) * (1.f + Ec)), c);
            if (wrOK) {
                if (last && hiH) {
                    sH2f[jj * NB + col] = h;        // h2(511) for the FC
                } else {
                    bw[wH] = (_Float16)h;           // single copy
                }
            }
        }
        if (xstage)                                  // x(s+1) -> write panel
            ((unsigned*)bw)[xwr] = sXu[((s + 1) & (SEQ - 1)) * NB + col];
        __syncthreads();   // the ONLY barrier per step
    };

    body(0, sB[0], sB[1], true, false, false);
    #pragma unroll 1
    for (int i = 0; i < 255; ++i) {
        body(2 * i + 1, sB[1], sB[0], true, true, false);
        body(2 * i + 2, sB[0], sB[1], true, true, false);
    }
    body(511, sB[1], sB[0], true, true, false);
    body(512, sB[0], sB[1], false, true, true);

    // ---- FC epilogue: out[b] = fcW . h2_last[b] + fcb ----
    if (t < NB) {
        float sum = fcb[0];
        #pragma unroll
        for (int jx = 0; jx < H; ++jx) sum += fcW[jx] * sH2f[jx * NB + t];
        out[bbase + t] = sum;
    }
}

extern "C" void kernel_launch(void* const* d_in, const int* in_sizes, int n_in,
                              void* d_out, int out_size, void* d_ws, size_t ws_size,
                              hipStream_t stream)
{
    const float* x    = (const float*)d_in[0];
    const float* Wih0 = (const float*)d_in[1];
    const float* Whh0 = (const float*)d_in[2];
    const float* bih0 = (const float*)d_in[3];
    const float* bhh0 = (const float*)d_in[4];
    const float* Wih1 = (const float*)d_in[5];
    const float* Whh1 = (const float*)d_in[6];
    const float* bih1 = (const float*)d_in[7];
    const float* bhh1 = (const float*)d_in[8];
    const float* fcW  = (const float*)d_in[9];
    const float* fcb  = (const float*)d_in[10];

    lstm2_r17<<<BATCH / NB, NT, 0, stream>>>(
        x, Wih0, Whh0, bih0, bhh0, Wih1, Whh1, bih1, bhh1, fcW, fcb,
        (float*)d_out);
}